// Round 9
// baseline (238.475 us; speedup 1.0000x reference)
//
#include <hip/hip_runtime.h>
#include <hip/hip_bf16.h>
#include <math.h>

#define EMBED 768
#define NHEAD 12
#define HDIM 64
#define SEQ 2048
#define BATCH 4

typedef __hip_bfloat16 bf16;
typedef __attribute__((ext_vector_type(8))) short bf16x8;   // 8 bf16 / 4 VGPRs
typedef __attribute__((ext_vector_type(4))) short s16x4;
typedef __attribute__((ext_vector_type(4))) float f32x4;
typedef __attribute__((ext_vector_type(2))) unsigned int u32x2;

__device__ inline float b2f(bf16 v) { return __bfloat162float(v); }
__device__ inline bf16 f2b(float v) { return __float2bfloat16(v); }
__device__ inline unsigned pk2(float a, float b) {
  return (unsigned)__bfloat16_as_ushort(f2b(a)) |
         ((unsigned)__bfloat16_as_ushort(f2b(b)) << 16);
}

// async global->LDS, 16B per lane. LDS dest = wave-uniform base + lane*16.
__device__ inline void gl_lds16(const bf16* g, bf16* l) {
  __builtin_amdgcn_global_load_lds(
      (const __attribute__((address_space(1))) void*)g,
      (__attribute__((address_space(3))) void*)l, 16, 0, 0);
}

#define NX4  (BATCH * SEQ * EMBED / 4)
#define NWQ4 (3 * EMBED * EMBED / 4)
#define NWP4 (EMBED * EMBED / 4)

// ---------------------------------------------------------------------------
// One fused f32->bf16 convert for x, w_qkv, w_proj (segmented index space).
// ---------------------------------------------------------------------------
__global__ __launch_bounds__(256) void cvt_all(
    const float* __restrict__ x, const float* __restrict__ wq,
    const float* __restrict__ wp, bf16* __restrict__ xb,
    bf16* __restrict__ wqb, bf16* __restrict__ wpb) {
  int i = blockIdx.x * 256 + threadIdx.x;
  const float* src;
  bf16* dst;
  int k;
  if (i < NX4) {
    src = x; dst = xb; k = i;
  } else if (i < NX4 + NWQ4) {
    src = wq; dst = wqb; k = i - NX4;
  } else if (i < NX4 + NWQ4 + NWP4) {
    src = wp; dst = wpb; k = i - NX4 - NWQ4;
  } else {
    return;
  }
  float4 v = ((const float4*)src)[k];
  s16x4 o;
  o[0] = (short)__bfloat16_as_ushort(f2b(v.x));
  o[1] = (short)__bfloat16_as_ushort(f2b(v.y));
  o[2] = (short)__bfloat16_as_ushort(f2b(v.z));
  o[3] = (short)__bfloat16_as_ushort(f2b(v.w));
  *(s16x4*)(dst + 4 * (size_t)k) = o;
}

// ---------------------------------------------------------------------------
// R21: QKV GEMM — 8-phase 256^2 template port (m201/m218 schedule, plain HIP).
//   256x256 tile, 512 threads / 8 waves (2M x 4N), BK=64, LDS 128 KB dbuf.
//   Per K-tile t (buf p=t&1), 4 phases; phase q:
//     - ds_read xf for j-pair {2q,2q+1} (4 b128); q==0 also reads wf (8 b128,
//       register-cached for the whole tile)
//     - stage ONE half-tile: q0:A0(t+1)->As[p^1], q1:A1(t+1)->As[p^1],
//       q2:B0(t+2)->Bs[p], q3:B1(t+2)->Bs[p]
//     - q3 only: s_waitcnt vmcnt(4) AFTER the stage — leaves exactly the 2
//       B(t+2) half-tiles (4 loads) in flight; guarantees tile t+1 fully
//       landed (counted per-wave: carry-in 4 + 8 issued - vmcnt(4) horizon).
//       Tail: vmcnt(0) when t+2 >= NSTEP.
//     - raw s_barrier (NO vmcnt0 drain — the T4 lever), setprio(1),
//       16 MFMA (4i x 2j x 2kh), setprio(0), raw s_barrier.
//   WAR audit: B-halves of buf p are read ONLY in phase 0 (wf reg-cached) ->
//   staging B(t+2) into buf p at phases 2/3 is safe; A rows 32q of buf p are
//   consumed in phase q, and A-stages only target buf p^1 (free since tile
//   t-1's last barrier). Max wave skew = 1 barrier interval (audited).
//   Accumulation order per output element identical to R8 (same kh/tile
//   sequence) -> numerics unchanged.
//   Grid 288 (8 XCD x 36; 4 m-rows x 9 n per XCD — R8's proven L2 chunking).
// Epilogue (verified R11/R12): Q(x 0.125*log2e)->[B,H,N,D], K->[B,H,N,D],
//   V->[B,H,D,N] (bf16). which = ob/EMBED block-uniform (256 | 768 aligned).
// ---------------------------------------------------------------------------
__global__ __launch_bounds__(512, 2) void gemm_qkv(
    const bf16* __restrict__ A, const bf16* __restrict__ W,
    const float* __restrict__ bias, bf16* __restrict__ outQ,
    bf16* __restrict__ outK, bf16* __restrict__ outV) {
  __shared__ bf16 As[2][256][64];   // 64 KB
  __shared__ bf16 Bs[2][256][64];   // 64 KB
  constexpr int KK = EMBED;         // 768
  constexpr int NSTEP = KK / 64;    // 12 K-tiles (even -> dbuf parity ok)

  const int t = threadIdx.x;
  const int w = t >> 6;             // 0..7
  const int lane = t & 63;
  const int g = lane >> 4, c = lane & 15;

  // XCD L2 chunking: 288 blocks = 8 xcd x 36; xcd gets 4 m-rows x 9 n-cols
  const int bid = blockIdx.x;
  const int xcd = bid & 7, idx = bid >> 3;
  const int m0 = (xcd * 4 + idx / 9) * 256;
  const int n0 = (idx % 9) * 256;

  const int wr = (w >> 2) * 128;    // wave m-base (As rows)
  const int wc = (w & 3) * 64;      // wave o-base (Bs rows)

  // staging lane mapping (both-sides chunk-XOR, verified R2+)
  const int r8 = lane >> 3;
  const int sseg = ((lane & 7) ^ r8) * 8;

  // stage one 128-row half-tile (2 gl_lds16/thread): wave w covers rows
  // (rnd*8+w)*8 .. +8 of the half; src row = row0 + rb + r8.
  auto stage = [&](const bf16* mat, int row0, int kt, bf16* dst) {
#pragma unroll
    for (int rnd = 0; rnd < 2; rnd++) {
      const int rb = (rnd * 8 + w) * 8;
      gl_lds16(mat + (size_t)(row0 + rb + r8) * KK + kt * 64 + sseg,
               dst + rb * 64);
    }
  };

  f32x4 acc[4][8] = {};   // acc[i][j]: i over o-frags, j over m-frags
  bf16x8 wf[4][2];        // register-cached B fragments, reloaded each tile

  // prologue: tile0 (A0,A1,B0,B1) + B0(1),B1(1); vmcnt(4) -> tile0 landed,
  // B(1) halves (4 loads) in flight.
  stage(A, m0, 0, &As[0][0][0]);
  stage(A, m0 + 128, 0, &As[0][128][0]);
  stage(W, n0, 0, &Bs[0][0][0]);
  stage(W, n0 + 128, 0, &Bs[0][128][0]);
  stage(W, n0, 1, &Bs[1][0][0]);
  stage(W, n0 + 128, 1, &Bs[1][128][0]);
  asm volatile("s_waitcnt vmcnt(4)" ::: "memory");
  __builtin_amdgcn_s_barrier();
  asm volatile("" ::: "memory");

  for (int s = 0; s < NSTEP; s++) {
    const int p = s & 1;
#pragma unroll
    for (int q = 0; q < 4; q++) {
      // ds-reads for this phase's j-pair (+ wf once per tile)
      bf16x8 xf[2][2];
#pragma unroll
      for (int d = 0; d < 2; d++)
#pragma unroll
        for (int kh = 0; kh < 2; kh++)
          xf[d][kh] = *(const bf16x8*)
              &As[p][wr + (q * 2 + d) * 16 + c][((kh * 4 + g) ^ (c & 7)) * 8];
      if (q == 0) {
#pragma unroll
        for (int i = 0; i < 4; i++)
#pragma unroll
          for (int kh = 0; kh < 2; kh++)
            wf[i][kh] = *(const bf16x8*)
                &Bs[p][wc + i * 16 + c][((kh * 4 + g) ^ (c & 7)) * 8];
      }

      // stage schedule (one half-tile per phase) + counted vmcnt at q3
      if (q == 0) {
        if (s + 1 < NSTEP) stage(A, m0, s + 1, &As[p ^ 1][0][0]);
      } else if (q == 1) {
        if (s + 1 < NSTEP) stage(A, m0 + 128, s + 1, &As[p ^ 1][128][0]);
      } else if (q == 2) {
        if (s + 2 < NSTEP) stage(W, n0, s + 2, &Bs[p][0][0]);
      } else {
        if (s + 2 < NSTEP) {
          stage(W, n0 + 128, s + 2, &Bs[p][128][0]);
          asm volatile("s_waitcnt vmcnt(4)" ::: "memory");
        } else {
          asm volatile("s_waitcnt vmcnt(0)" ::: "memory");
        }
      }

      asm volatile("" ::: "memory");
      __builtin_amdgcn_s_barrier();
      asm volatile("" ::: "memory");

      __builtin_amdgcn_s_setprio(1);
#pragma unroll
      for (int i = 0; i < 4; i++)
#pragma unroll
        for (int d = 0; d < 2; d++)
#pragma unroll
          for (int kh = 0; kh < 2; kh++)
            acc[i][q * 2 + d] = __builtin_amdgcn_mfma_f32_16x16x32_bf16(
                wf[i][kh], xf[d][kh], acc[i][q * 2 + d], 0, 0, 0);
      __builtin_amdgcn_s_setprio(0);

      asm volatile("" ::: "memory");
      __builtin_amdgcn_s_barrier();
      asm volatile("" ::: "memory");
    }
  }

  // epilogue: D^T tile — row = o (4 consecutive per thread), col = m (lane c)
#pragma unroll
  for (int i = 0; i < 4; i++) {
    const int ob = n0 + wc + i * 16 + g * 4;     // o base, +r consecutive
    const f32x4 bv = *(const f32x4*)&bias[ob];   // 16B-aligned
    const int which = ob / EMBED;
    const int rem = ob - which * EMBED;
    const int hh = rem >> 6;
    const int d0 = rem & 63;
#pragma unroll
    for (int j = 0; j < 8; j++) {
      const int m = m0 + wr + j * 16 + c;
      f32x4 v = acc[i][j] + bv;
      const int bb = m >> 11, n = m & 2047;
      const size_t bh = (size_t)bb * NHEAD + hh;
      if (which == 0) {
        s16x4 q4;
#pragma unroll
        for (int r = 0; r < 4; r++)
          q4[r] = (short)__bfloat16_as_ushort(f2b(v[r] * 0.1803368801f));
        *(s16x4*)&outQ[(bh * SEQ + n) * HDIM + d0] = q4;
      } else if (which == 1) {
        s16x4 k4;
#pragma unroll
        for (int r = 0; r < 4; r++)
          k4[r] = (short)__bfloat16_as_ushort(f2b(v[r]));
        *(s16x4*)&outK[(bh * SEQ + n) * HDIM + d0] = k4;
      } else {
#pragma unroll
        for (int r = 0; r < 4; r++)
          outV[(bh * HDIM + d0 + r) * SEQ + n] = f2b(v[r]);
      }
    }
  }
}

// ---------------------------------------------------------------------------
// proj GEMM — R5/R8-verified 128x64 structure (single-buf BK=64, 2 barriers,
// both-sides XOR swizzle, LB(256,5), XCD m-row chunking). outF f32 row-major.
// ---------------------------------------------------------------------------
__global__ __launch_bounds__(256, 5) void gemm_proj(
    const bf16* __restrict__ A, const bf16* __restrict__ W,
    const float* __restrict__ bias, float* __restrict__ outF, int N, int K) {
  constexpr int TM = 64;
  __shared__ bf16 As[TM][64];
  __shared__ bf16 Bs[128][64];
  const int t = threadIdx.x;
  const int w = t >> 6;
  const int lane = t & 63;
  const int g = lane >> 4, c = lane & 15;

  // XCD chunking: 768 blocks = 8 xcd x 96; xcd gets 16 m-rows x 6 n-cols
  const int bid = blockIdx.x;
  const int xcd = bid & 7;
  const int idx = bid >> 3;
  const int mr = xcd * 16 + idx / 6;
  const int nc = idx % 6;
  const int m0 = mr * TM, n0 = nc * 128;

  constexpr int MJ = TM / 32;          // 2
  const int wr = (w >> 1) * (TM / 2);
  const int wc = (w & 1) * 64;

  const int srow = lane >> 3;
  const int l8 = lane & 7;
  const int sseg = (l8 ^ srow) * 8;

  f32x4 acc[4][MJ] = {};

  for (int k0 = 0; k0 < K; k0 += 64) {
#pragma unroll
    for (int i = 0; i < 4; i++) {
      int r = w * 32 + i * 8;
      gl_lds16(W + (size_t)(n0 + r + srow) * K + k0 + sseg, &Bs[r][0]);
    }
#pragma unroll
    for (int i = 0; i < TM / 32; i++) {
      int r = w * (TM / 4) + i * 8;
      gl_lds16(A + (size_t)(m0 + r + srow) * K + k0 + sseg, &As[r][0]);
    }
    __syncthreads();

#pragma unroll
    for (int h = 0; h < 2; h++) {
      bf16x8 xf[MJ], wf[4];
#pragma unroll
      for (int j = 0; j < MJ; j++)
        xf[j] = *(const bf16x8*)&As[wr + j * 16 + c][((h * 4 + g) ^ (c & 7)) * 8];
#pragma unroll
      for (int i = 0; i < 4; i++)
        wf[i] = *(const bf16x8*)&Bs[wc + i * 16 + c][((h * 4 + g) ^ (c & 7)) * 8];
#pragma unroll
      for (int i = 0; i < 4; i++)
#pragma unroll
        for (int j = 0; j < MJ; j++)
          acc[i][j] = __builtin_amdgcn_mfma_f32_16x16x32_bf16(wf[i], xf[j],
                                                              acc[i][j], 0, 0, 0);
    }
    __syncthreads();
  }

#pragma unroll
  for (int i = 0; i < 4; i++) {
    const int ob = n0 + wc + i * 16 + g * 4;
    const f32x4 bv = *(const f32x4*)&bias[ob];
#pragma unroll
    for (int j = 0; j < MJ; j++) {
      const int m = m0 + wr + j * 16 + c;
      f32x4 v = acc[i][j] + bv;
      *(f32x4*)&outF[(size_t)m * N + ob] = v;
    }
  }
}

// ---------------------------------------------------------------------------
// Flash MFMA attention v7 — measured-best structure, FROZEN since R2.
// R21: XCD swizzle REVERTED (R8: FETCH 104->18.5MB but dur 83.0->84.4 —
// attn is not drain-bound; the remap itself cost ~1.2 µs).
//   S^T = K . Q^T ; O^T = V^T . P^T  (fragment maps verified R3-R12)
// Block = 128 q-rows, 4 waves x 2 groups of 16. LDS 34.8 KB; grid 768 = 3/CU.
// Per iter: S(ks) -> B1 -> DMA K(jt+1) -> softmax/Pt/PV(vs) -> B2 -> DMA V(jt+1).
// ---------------------------------------------------------------------------
__global__ __launch_bounds__(256, 4) void attn_mfma(
    const bf16* __restrict__ Q, const bf16* __restrict__ Kk,
    const bf16* __restrict__ V, bf16* __restrict__ O) {
  __shared__ bf16 Ks[64 * 64];
  __shared__ bf16 Vts[64 * 64];
  __shared__ bf16 Pt[8][16 * 72];

  const int blk = blockIdx.x;
  const int bh = blk >> 4;               // 16 q-tiles (of 128) per (b,h)
  const int qt = blk & 15;
  const int bb = bh / NHEAD;
  const int h = bh % NHEAD;
  const int t = threadIdx.x;
  const int lane = t & 63;
  const int w = t >> 6;
  const int g = lane >> 4;
  const int c = lane & 15;
  const size_t base = (size_t)bh * SEQ * HDIM;
  const int mb0 = qt * 128 + w * 16;     // q-group 0 rows
  const int mb1 = mb0 + 64;              // q-group 1 rows

  // DMA lane mapping (XOR chunk swizzle for K/V, verified R5-R12)
  const int r8 = lane >> 3;
  const int l8 = lane & 7;
  const int gch = l8 ^ (r8 & 7);
  const int q0 = w * 2, q1 = w * 2 + 1;

  // Q fragments (B operand), one pair per q-group
  bf16x8 qa[2][2];
#pragma unroll
  for (int kh = 0; kh < 2; kh++) {
    qa[0][kh] = *(const bf16x8*)(Q + base + (size_t)(mb0 + c) * HDIM + kh * 32 + g * 8);
    qa[1][kh] = *(const bf16x8*)(Q + base + (size_t)(mb1 + c) * HDIM + kh * 32 + g * 8);
  }

  // all-ones A fragment for the l-row-sum MFMA
  bf16x8 ones;
#pragma unroll
  for (int i = 0; i < 8; i++) ones[i] = (short)0x3F80;

  f32x4 o[2][4] = {};
  f32x4 o_l[2] = {};

  // prologue: DMA tile 0 (K and V), drain before first use
  gl_lds16(Kk + base + (size_t)(q0 * 8 + r8) * HDIM + gch * 8, &Ks[q0 * 8 * 64]);
  gl_lds16(Kk + base + (size_t)(q1 * 8 + r8) * HDIM + gch * 8, &Ks[q1 * 8 * 64]);
  gl_lds16(V + base + (size_t)(q0 * 8 + r8) * SEQ + gch * 8, &Vts[q0 * 8 * 64]);
  gl_lds16(V + base + (size_t)(q1 * 8 + r8) * SEQ + gch * 8, &Vts[q1 * 8 * 64]);
  __syncthreads();

  bf16* const Pt0 = Pt[w * 2];
  bf16* const Pt1 = Pt[w * 2 + 1];

  for (int jt = 0; jt < SEQ / 64; jt++) {
    // S^T = K . Q^T — each kb read feeds both q-groups
    f32x4 s[2][4] = {};
#pragma unroll
    for (int nt = 0; nt < 4; nt++) {
#pragma unroll
      for (int kh = 0; kh < 2; kh++) {
        bf16x8 kb = *(const bf16x8*)&Ks[(nt * 16 + c) * 64 + ((kh * 4 + g) ^ (c & 7)) * 8];
        s[0][nt] = __builtin_amdgcn_mfma_f32_16x16x32_bf16(kb, qa[0][kh], s[0][nt], 0, 0, 0);
        s[1][nt] = __builtin_amdgcn_mfma_f32_16x16x32_bf16(kb, qa[1][kh], s[1][nt], 0, 0, 0);
      }
    }

    __syncthreads();  // B1: all waves done reading Ks; drains V(jt) DMA
    if (jt + 1 < SEQ / 64) {  // DMA K(jt+1); softmax+PV time to land
      const int jb = (jt + 1) * 64;
      gl_lds16(Kk + base + (size_t)(jb + q0 * 8 + r8) * HDIM + gch * 8, &Ks[q0 * 8 * 64]);
      gl_lds16(Kk + base + (size_t)(jb + q1 * 8 + r8) * HDIM + gch * 8, &Ks[q1 * 8 * 64]);
    }

    // p = exp2(s); pack 4 consecutive j; plain stride-72 Pt, per group
#pragma unroll
    for (int nt = 0; nt < 4; nt++) {
      float a0 = __builtin_amdgcn_exp2f(s[0][nt][0]);
      float a1 = __builtin_amdgcn_exp2f(s[0][nt][1]);
      float a2 = __builtin_amdgcn_exp2f(s[0][nt][2]);
      float a3 = __builtin_amdgcn_exp2f(s[0][nt][3]);
      u32x2 pw0 = {pk2(a0, a1), pk2(a2, a3)};
      *(u32x2*)&Pt0[c * 72 + nt * 16 + g * 4] = pw0;
      float b0 = __builtin_amdgcn_exp2f(s[1][nt][0]);
      float b1 = __builtin_amdgcn_exp2f(s[1][nt][1]);
      float b2 = __builtin_amdgcn_exp2f(s[1][nt][2]);
      float b3 = __builtin_amdgcn_exp2f(s[1][nt][3]);
      u32x2 pw1 = {pk2(b0, b1), pk2(b2, b3)};
      *(u32x2*)&Pt1[c * 72 + nt * 16 + g * 4] = pw1;
    }
    bf16x8 pb[2][2];
    pb[0][0] = *(const bf16x8*)&Pt0[c * 72 + g * 8];
    pb[0][1] = *(const bf16x8*)&Pt0[c * 72 + 32 + g * 8];
    pb[1][0] = *(const bf16x8*)&Pt1[c * 72 + g * 8];
    pb[1][1] = *(const bf16x8*)&Pt1[c * 72 + 32 + g * 8];

    // O^T += V^T . P^T — each vb read feeds both q-groups;
    // l += ones . P^T in the MFMA pipe
#pragma unroll
    for (int dt = 0; dt < 4; dt++) {
      bf16x8 vb0 = *(const bf16x8*)&Vts[(dt * 16 + c) * 64 + ((0 + g) ^ (c & 7)) * 8];
      bf16x8 vb1 = *(const bf16x8*)&Vts[(dt * 16 + c) * 64 + ((4 + g) ^ (c & 7)) * 8];
      o[0][dt] = __builtin_amdgcn_mfma_f32_16x16x32_bf16(vb0, pb[0][0], o[0][dt], 0, 0, 0);
      o[0][dt] = __builtin_amdgcn_mfma_f32_16x16x32_bf16(vb1, pb[0][1], o[0][dt], 0, 0, 0);
      o[1][dt] = __builtin_amdgcn_mfma_f32_16x16x32_bf16(vb0, pb[1][0], o[1][dt], 0, 0, 0);
      o[1][dt] = __builtin_amdgcn_mfma_f32_16x16x32_bf16(vb1, pb[1][1], o[1][dt], 0, 0, 0);
    }
    o_l[0] = __builtin_amdgcn_mfma_f32_16x16x32_bf16(ones, pb[0][0], o_l[0], 0, 0, 0);
    o_l[0] = __builtin_amdgcn_mfma_f32_16x16x32_bf16(ones, pb[0][1], o_l[0], 0, 0, 0);
    o_l[1] = __builtin_amdgcn_mfma_f32_16x16x32_bf16(ones, pb[1][0], o_l[1], 0, 0, 0);
    o_l[1] = __builtin_amdgcn_mfma_f32_16x16x32_bf16(ones, pb[1][1], o_l[1], 0, 0, 0);

    __syncthreads();  // B2: all waves done reading Vts; drains K(jt+1) DMA
    if (jt + 1 < SEQ / 64) {  // DMA V(jt+1); S-phase time to land
      const int jb = (jt + 1) * 64;
      gl_lds16(V + base + (size_t)(q0 * 8 + r8) * SEQ + jb + gch * 8, &Vts[q0 * 8 * 64]);
      gl_lds16(V + base + (size_t)(q1 * 8 + r8) * SEQ + jb + gch * 8, &Vts[q1 * 8 * 64]);
    }
  }

  // epilogue: l[c] replicated in every o_l reg — no shuffles; packed stores
#pragma unroll
  for (int grp = 0; grp < 2; grp++) {
    const float inv = __builtin_amdgcn_rcpf(o_l[grp][0]);
    const int mb = grp ? mb1 : mb0;
    const size_t rowoff = ((size_t)bb * SEQ + mb + c) * EMBED + h * 64 + g * 4;
#pragma unroll
    for (int dt = 0; dt < 4; dt++) {
      s16x4 ov;
#pragma unroll
      for (int r = 0; r < 4; r++)
        ov[r] = (short)__bfloat16_as_ushort(f2b(o[grp][dt][r] * inv));
      *(s16x4*)&O[rowoff + dt * 16] = ov;
    }
  }
}

// ---------------------------------------------------------------------------
extern "C" void kernel_launch(void* const* d_in, const int* in_sizes, int n_in,
                              void* d_out, int out_size, void* d_ws,
                              size_t ws_size, hipStream_t stream) {
  const float* x      = (const float*)d_in[0];
  const float* w_qkv  = (const float*)d_in[1];
  const float* b_qkv  = (const float*)d_in[2];
  const float* w_proj = (const float*)d_in[3];
  const float* b_proj = (const float*)d_in[4];

  const size_t per = (size_t)BATCH * NHEAD * SEQ * HDIM;
  bf16* Qp = (bf16*)d_ws;
  bf16* Kp = Qp + per;
  bf16* Vp = Kp + per;                 // [B,H,D,N]
  bf16* xb = Vp + per;                 // x bf16; reused as AO after QKV GEMM
  bf16* wqkvb = xb + per;
  bf16* wprojb = wqkvb + (size_t)3 * EMBED * EMBED;
  bf16* AO = xb;

  const int ncvt = NX4 + NWQ4 + NWP4;  // f32x4 groups total
  cvt_all<<<dim3((ncvt + 255) / 256), 256, 0, stream>>>(x, w_qkv, w_proj, xb,
                                                        wqkvb, wprojb);

  // QKV GEMM: 8-phase 256^2, 512 threads, grid 288 (XCD-chunked)
  gemm_qkv<<<dim3(288), 512, 0, stream>>>(xb, wqkvb, b_qkv, Qp, Kp, Vp);

  // attn: 768 blocks (original decode), 34.8 KB LDS, 3/CU
  attn_mfma<<<dim3(BATCH * NHEAD * (SEQ / 128)), 256, 0, stream>>>(Qp, Kp, Vp, AO);

  // proj GEMM: 1D grid 768 (6 n x 128 m), XCD m-row chunking, 5 blocks/CU
  gemm_proj<<<dim3(768), 256, 0, stream>>>(AO, wprojb, b_proj, (float*)d_out,
                                           EMBED, EMBED);
}

// Round 10
// 221.167 us; speedup vs baseline: 1.0783x; 1.0783x over previous
//
#include <hip/hip_runtime.h>
#include <hip/hip_bf16.h>
#include <math.h>

#define EMBED 768
#define NHEAD 12
#define HDIM 64
#define SEQ 2048
#define BATCH 4

typedef __hip_bfloat16 bf16;
typedef __attribute__((ext_vector_type(8))) short bf16x8;   // 8 bf16 / 4 VGPRs
typedef __attribute__((ext_vector_type(4))) short s16x4;
typedef __attribute__((ext_vector_type(4))) float f32x4;
typedef __attribute__((ext_vector_type(2))) unsigned int u32x2;

__device__ inline float b2f(bf16 v) { return __bfloat162float(v); }
__device__ inline bf16 f2b(float v) { return __float2bfloat16(v); }
__device__ inline unsigned pk2(float a, float b) {
  return (unsigned)__bfloat16_as_ushort(f2b(a)) |
         ((unsigned)__bfloat16_as_ushort(f2b(b)) << 16);
}

// async global->LDS, 16B per lane. LDS dest = wave-uniform base + lane*16.
__device__ inline void gl_lds16(const bf16* g, bf16* l) {
  __builtin_amdgcn_global_load_lds(
      (const __attribute__((address_space(1))) void*)g,
      (__attribute__((address_space(3))) void*)l, 16, 0, 0);
}

#define NX4  (BATCH * SEQ * EMBED / 4)
#define NWQ4 (3 * EMBED * EMBED / 4)
#define NWP4 (EMBED * EMBED / 4)

// ---------------------------------------------------------------------------
// One fused f32->bf16 convert for x, w_qkv, w_proj (segmented index space).
// Near memory roofline (~67MB traffic ~ 10.6 µs floor).
// ---------------------------------------------------------------------------
__global__ __launch_bounds__(256) void cvt_all(
    const float* __restrict__ x, const float* __restrict__ wq,
    const float* __restrict__ wp, bf16* __restrict__ xb,
    bf16* __restrict__ wqb, bf16* __restrict__ wpb) {
  int i = blockIdx.x * 256 + threadIdx.x;
  const float* src;
  bf16* dst;
  int k;
  if (i < NX4) {
    src = x; dst = xb; k = i;
  } else if (i < NX4 + NWQ4) {
    src = wq; dst = wqb; k = i - NX4;
  } else if (i < NX4 + NWQ4 + NWP4) {
    src = wp; dst = wpb; k = i - NX4 - NWQ4;
  } else {
    return;
  }
  float4 v = ((const float4*)src)[k];
  s16x4 o;
  o[0] = (short)__bfloat16_as_ushort(f2b(v.x));
  o[1] = (short)__bfloat16_as_ushort(f2b(v.y));
  o[2] = (short)__bfloat16_as_ushort(f2b(v.z));
  o[3] = (short)__bfloat16_as_ushort(f2b(v.w));
  *(s16x4*)(dst + 4 * (size_t)k) = o;
}

// ---------------------------------------------------------------------------
// MFMA GEMM — R22: CONSOLIDATED BEST (R8's exact gemm config).
// Session verdict (R2-R9): this shape (M=8192, N<=2304, K=768) lives in the
// small-tile/high-residency regime. Measured-best levers ONLY:
//   * single-buf BK=64, 2 __syncthreads/step (R2: +16 µs vs BK=32)
//   * both-sides XOR swizzle (R2, verified)
//   * LB(256,WPB): occupancy 4-5 blocks/CU (R5: +2 µs)
//   * XCD m-row chunking for L2 residency (R8: ~+10 µs across gemms;
//     FETCH-verified mechanism)
// Rejected by measurement: dbuf depth-1 (R3), depth-2 counted vmcnt (R4),
// 256^2 2-phase (R6), 128x256 wave-ratio (R7), 8-phase 256^2 port (R9 —
// 1 block/CU + grid 288 tail + 12-tile pipeline can't amortize; the m201
// template's prereq is SCALE, not just structure).
//   MODE 0 (TM=128): grid 1152; xcd=bid&7 gets m-rows [8k,8k+8) x 18 n.
//   MODE 1 (TM=64):  grid 768;  xcd=bid&7 gets m-rows [16k,16k+16) x 6 n.
// MODE 0 epilogue (verified R11/R12): Q(x 0.125*log2e)->[B,H,N,D],
// K->[B,H,N,D], V->[B,H,D,N] (bf16).  MODE 1: outF[m,o] f32 row-major.
// ---------------------------------------------------------------------------
template <int MODE, int TM, int WPB>
__global__ __launch_bounds__(256, WPB) void gemm_mfma(
    const bf16* __restrict__ A, const bf16* __restrict__ W,
    const float* __restrict__ bias, float* __restrict__ outF,
    bf16* __restrict__ outQ, bf16* __restrict__ outK, bf16* __restrict__ outV,
    int M, int N, int K) {
  __shared__ bf16 As[TM][64];
  __shared__ bf16 Bs[128][64];
  const int t = threadIdx.x;
  const int w = t >> 6;
  const int lane = t & 63;
  const int g = lane >> 4, c = lane & 15;

  // XCD locality decode (bijective)
  const int bid = blockIdx.x;
  const int xcd = bid & 7;
  const int idx = bid >> 3;
  constexpr int NT = (MODE == 0) ? 18 : 6;          // n-tiles
  constexpr int MRX = (MODE == 0) ? 8 : 16;         // m-rows per XCD
  const int mr = xcd * MRX + idx / NT;
  const int nc = idx % NT;
  const int m0 = mr * TM, n0 = nc * 128;

  constexpr int MJ = TM / 32;          // m-frags per wave: 4 (TM=128) / 2 (64)
  const int wr = (w >> 1) * (TM / 2);  // m-dim tile base (As)
  const int wc = (w & 1) * 64;         // o-dim tile base (Bs)

  // DMA mapping: 1KB per instr = 8 rows x 128B. Source chunk pre-swizzled.
  const int srow = lane >> 3;          // 0..7 row within 8-row stripe
  const int l8 = lane & 7;             // LDS 16B-slot within row
  const int sseg = (l8 ^ srow) * 8;    // swizzled global chunk (bf16 elems)

  f32x4 acc[4][MJ] = {};  // acc[i][j]: i over o-tiles (W), j over m-tiles (x)

  for (int k0 = 0; k0 < K; k0 += 64) {
#pragma unroll
    for (int i = 0; i < 4; i++) {
      int r = w * 32 + i * 8;
      gl_lds16(W + (size_t)(n0 + r + srow) * K + k0 + sseg, &Bs[r][0]);
    }
#pragma unroll
    for (int i = 0; i < TM / 32; i++) {
      int r = w * (TM / 4) + i * 8;
      gl_lds16(A + (size_t)(m0 + r + srow) * K + k0 + sseg, &As[r][0]);
    }
    __syncthreads();

#pragma unroll
    for (int h = 0; h < 2; h++) {
      bf16x8 xf[MJ], wf[4];
#pragma unroll
      for (int j = 0; j < MJ; j++)
        xf[j] = *(const bf16x8*)&As[wr + j * 16 + c][((h * 4 + g) ^ (c & 7)) * 8];
#pragma unroll
      for (int i = 0; i < 4; i++)
        wf[i] = *(const bf16x8*)&Bs[wc + i * 16 + c][((h * 4 + g) ^ (c & 7)) * 8];
#pragma unroll
      for (int i = 0; i < 4; i++)
#pragma unroll
        for (int j = 0; j < MJ; j++)
          acc[i][j] = __builtin_amdgcn_mfma_f32_16x16x32_bf16(wf[i], xf[j],
                                                              acc[i][j], 0, 0, 0);
    }
    __syncthreads();
  }

  // epilogue: D^T tile — row = o (4 consecutive per thread), col = m (lane c)
#pragma unroll
  for (int i = 0; i < 4; i++) {
    const int ob = n0 + wc + i * 16 + g * 4;     // o base, +r consecutive
    const f32x4 bv = *(const f32x4*)&bias[ob];   // 16B-aligned
    int which = 0, hh = 0, d0 = 0;
    if (MODE == 0) {
      which = ob / EMBED;
      int rem = ob - which * EMBED;
      hh = rem >> 6;
      d0 = rem & 63;
    }
#pragma unroll
    for (int j = 0; j < MJ; j++) {
      const int m = m0 + wr + j * 16 + c;
      f32x4 v = acc[i][j] + bv;
      if (MODE == 0) {
        const int bb = m >> 11, n = m & 2047;
        const size_t bh = (size_t)bb * NHEAD + hh;
        if (which == 0) {
          s16x4 q4;
#pragma unroll
          for (int r = 0; r < 4; r++)
            q4[r] = (short)__bfloat16_as_ushort(f2b(v[r] * 0.1803368801f));
          *(s16x4*)&outQ[(bh * SEQ + n) * HDIM + d0] = q4;
        } else if (which == 1) {
          s16x4 k4;
#pragma unroll
          for (int r = 0; r < 4; r++)
            k4[r] = (short)__bfloat16_as_ushort(f2b(v[r]));
          *(s16x4*)&outK[(bh * SEQ + n) * HDIM + d0] = k4;
        } else {
#pragma unroll
          for (int r = 0; r < 4; r++)
            outV[(bh * HDIM + d0 + r) * SEQ + n] = f2b(v[r]);
        }
      } else {
        *(f32x4*)&outF[(size_t)m * N + ob] = v;
      }
    }
  }
}

// ---------------------------------------------------------------------------
// Flash MFMA attention v7 — measured-best structure, FROZEN since R2.
// Original block decode (R8's XCD swizzle cut FETCH 104->18.5MB but cost
// ~2 µs — attn is not drain-bound; reverted in R9, confirmed 82.4 µs).
//   S^T = K . Q^T ; O^T = V^T . P^T  (fragment maps verified R3-R12)
// Block = 128 q-rows, 4 waves x 2 groups of 16. LDS 34.8 KB; grid 768 = 3/CU.
// Per iter: S(ks) -> B1 -> DMA K(jt+1) -> softmax/Pt/PV(vs) -> B2 -> DMA V(jt+1).
// ---------------------------------------------------------------------------
__global__ __launch_bounds__(256, 4) void attn_mfma(
    const bf16* __restrict__ Q, const bf16* __restrict__ Kk,
    const bf16* __restrict__ V, bf16* __restrict__ O) {
  __shared__ bf16 Ks[64 * 64];
  __shared__ bf16 Vts[64 * 64];
  __shared__ bf16 Pt[8][16 * 72];

  const int blk = blockIdx.x;
  const int bh = blk >> 4;               // 16 q-tiles (of 128) per (b,h)
  const int qt = blk & 15;
  const int bb = bh / NHEAD;
  const int h = bh % NHEAD;
  const int t = threadIdx.x;
  const int lane = t & 63;
  const int w = t >> 6;
  const int g = lane >> 4;
  const int c = lane & 15;
  const size_t base = (size_t)bh * SEQ * HDIM;
  const int mb0 = qt * 128 + w * 16;     // q-group 0 rows
  const int mb1 = mb0 + 64;              // q-group 1 rows

  // DMA lane mapping (XOR chunk swizzle for K/V, verified R5-R12)
  const int r8 = lane >> 3;
  const int l8 = lane & 7;
  const int gch = l8 ^ (r8 & 7);
  const int q0 = w * 2, q1 = w * 2 + 1;

  // Q fragments (B operand), one pair per q-group
  bf16x8 qa[2][2];
#pragma unroll
  for (int kh = 0; kh < 2; kh++) {
    qa[0][kh] = *(const bf16x8*)(Q + base + (size_t)(mb0 + c) * HDIM + kh * 32 + g * 8);
    qa[1][kh] = *(const bf16x8*)(Q + base + (size_t)(mb1 + c) * HDIM + kh * 32 + g * 8);
  }

  // all-ones A fragment for the l-row-sum MFMA
  bf16x8 ones;
#pragma unroll
  for (int i = 0; i < 8; i++) ones[i] = (short)0x3F80;

  f32x4 o[2][4] = {};
  f32x4 o_l[2] = {};

  // prologue: DMA tile 0 (K and V), drain before first use
  gl_lds16(Kk + base + (size_t)(q0 * 8 + r8) * HDIM + gch * 8, &Ks[q0 * 8 * 64]);
  gl_lds16(Kk + base + (size_t)(q1 * 8 + r8) * HDIM + gch * 8, &Ks[q1 * 8 * 64]);
  gl_lds16(V + base + (size_t)(q0 * 8 + r8) * SEQ + gch * 8, &Vts[q0 * 8 * 64]);
  gl_lds16(V + base + (size_t)(q1 * 8 + r8) * SEQ + gch * 8, &Vts[q1 * 8 * 64]);
  __syncthreads();

  bf16* const Pt0 = Pt[w * 2];
  bf16* const Pt1 = Pt[w * 2 + 1];

  for (int jt = 0; jt < SEQ / 64; jt++) {
    // S^T = K . Q^T — each kb read feeds both q-groups
    f32x4 s[2][4] = {};
#pragma unroll
    for (int nt = 0; nt < 4; nt++) {
#pragma unroll
      for (int kh = 0; kh < 2; kh++) {
        bf16x8 kb = *(const bf16x8*)&Ks[(nt * 16 + c) * 64 + ((kh * 4 + g) ^ (c & 7)) * 8];
        s[0][nt] = __builtin_amdgcn_mfma_f32_16x16x32_bf16(kb, qa[0][kh], s[0][nt], 0, 0, 0);
        s[1][nt] = __builtin_amdgcn_mfma_f32_16x16x32_bf16(kb, qa[1][kh], s[1][nt], 0, 0, 0);
      }
    }

    __syncthreads();  // B1: all waves done reading Ks; drains V(jt) DMA
    if (jt + 1 < SEQ / 64) {  // DMA K(jt+1); softmax+PV time to land
      const int jb = (jt + 1) * 64;
      gl_lds16(Kk + base + (size_t)(jb + q0 * 8 + r8) * HDIM + gch * 8, &Ks[q0 * 8 * 64]);
      gl_lds16(Kk + base + (size_t)(jb + q1 * 8 + r8) * HDIM + gch * 8, &Ks[q1 * 8 * 64]);
    }

    // p = exp2(s); pack 4 consecutive j; plain stride-72 Pt, per group
#pragma unroll
    for (int nt = 0; nt < 4; nt++) {
      float a0 = __builtin_amdgcn_exp2f(s[0][nt][0]);
      float a1 = __builtin_amdgcn_exp2f(s[0][nt][1]);
      float a2 = __builtin_amdgcn_exp2f(s[0][nt][2]);
      float a3 = __builtin_amdgcn_exp2f(s[0][nt][3]);
      u32x2 pw0 = {pk2(a0, a1), pk2(a2, a3)};
      *(u32x2*)&Pt0[c * 72 + nt * 16 + g * 4] = pw0;
      float b0 = __builtin_amdgcn_exp2f(s[1][nt][0]);
      float b1 = __builtin_amdgcn_exp2f(s[1][nt][1]);
      float b2 = __builtin_amdgcn_exp2f(s[1][nt][2]);
      float b3 = __builtin_amdgcn_exp2f(s[1][nt][3]);
      u32x2 pw1 = {pk2(b0, b1), pk2(b2, b3)};
      *(u32x2*)&Pt1[c * 72 + nt * 16 + g * 4] = pw1;
    }
    bf16x8 pb[2][2];
    pb[0][0] = *(const bf16x8*)&Pt0[c * 72 + g * 8];
    pb[0][1] = *(const bf16x8*)&Pt0[c * 72 + 32 + g * 8];
    pb[1][0] = *(const bf16x8*)&Pt1[c * 72 + g * 8];
    pb[1][1] = *(const bf16x8*)&Pt1[c * 72 + 32 + g * 8];

    // O^T += V^T . P^T — each vb read feeds both q-groups;
    // l += ones . P^T in the MFMA pipe
#pragma unroll
    for (int dt = 0; dt < 4; dt++) {
      bf16x8 vb0 = *(const bf16x8*)&Vts[(dt * 16 + c) * 64 + ((0 + g) ^ (c & 7)) * 8];
      bf16x8 vb1 = *(const bf16x8*)&Vts[(dt * 16 + c) * 64 + ((4 + g) ^ (c & 7)) * 8];
      o[0][dt] = __builtin_amdgcn_mfma_f32_16x16x32_bf16(vb0, pb[0][0], o[0][dt], 0, 0, 0);
      o[0][dt] = __builtin_amdgcn_mfma_f32_16x16x32_bf16(vb1, pb[0][1], o[0][dt], 0, 0, 0);
      o[1][dt] = __builtin_amdgcn_mfma_f32_16x16x32_bf16(vb0, pb[1][0], o[1][dt], 0, 0, 0);
      o[1][dt] = __builtin_amdgcn_mfma_f32_16x16x32_bf16(vb1, pb[1][1], o[1][dt], 0, 0, 0);
    }
    o_l[0] = __builtin_amdgcn_mfma_f32_16x16x32_bf16(ones, pb[0][0], o_l[0], 0, 0, 0);
    o_l[0] = __builtin_amdgcn_mfma_f32_16x16x32_bf16(ones, pb[0][1], o_l[0], 0, 0, 0);
    o_l[1] = __builtin_amdgcn_mfma_f32_16x16x32_bf16(ones, pb[1][0], o_l[1], 0, 0, 0);
    o_l[1] = __builtin_amdgcn_mfma_f32_16x16x32_bf16(ones, pb[1][1], o_l[1], 0, 0, 0);

    __syncthreads();  // B2: all waves done reading Vts; drains K(jt+1) DMA
    if (jt + 1 < SEQ / 64) {  // DMA V(jt+1); S-phase time to land
      const int jb = (jt + 1) * 64;
      gl_lds16(V + base + (size_t)(q0 * 8 + r8) * SEQ + jb + gch * 8, &Vts[q0 * 8 * 64]);
      gl_lds16(V + base + (size_t)(q1 * 8 + r8) * SEQ + jb + gch * 8, &Vts[q1 * 8 * 64]);
    }
  }

  // epilogue: l[c] replicated in every o_l reg — no shuffles; packed stores
#pragma unroll
  for (int grp = 0; grp < 2; grp++) {
    const float inv = __builtin_amdgcn_rcpf(o_l[grp][0]);
    const int mb = grp ? mb1 : mb0;
    const size_t rowoff = ((size_t)bb * SEQ + mb + c) * EMBED + h * 64 + g * 4;
#pragma unroll
    for (int dt = 0; dt < 4; dt++) {
      s16x4 ov;
#pragma unroll
      for (int r = 0; r < 4; r++)
        ov[r] = (short)__bfloat16_as_ushort(f2b(o[grp][dt][r] * inv));
      *(s16x4*)&O[rowoff + dt * 16] = ov;
    }
  }
}

// ---------------------------------------------------------------------------
extern "C" void kernel_launch(void* const* d_in, const int* in_sizes, int n_in,
                              void* d_out, int out_size, void* d_ws,
                              size_t ws_size, hipStream_t stream) {
  const float* x      = (const float*)d_in[0];
  const float* w_qkv  = (const float*)d_in[1];
  const float* b_qkv  = (const float*)d_in[2];
  const float* w_proj = (const float*)d_in[3];
  const float* b_proj = (const float*)d_in[4];

  const size_t per = (size_t)BATCH * NHEAD * SEQ * HDIM;
  bf16* Qp = (bf16*)d_ws;
  bf16* Kp = Qp + per;
  bf16* Vp = Kp + per;                 // [B,H,D,N]
  bf16* xb = Vp + per;                 // x bf16; reused as AO after QKV GEMM
  bf16* wqkvb = xb + per;
  bf16* wprojb = wqkvb + (size_t)3 * EMBED * EMBED;
  bf16* AO = xb;

  const int ncvt = NX4 + NWQ4 + NWP4;  // f32x4 groups total
  cvt_all<<<dim3((ncvt + 255) / 256), 256, 0, stream>>>(x, w_qkv, w_proj, xb,
                                                        wqkvb, wprojb);

  // QKV GEMM: R8-exact — 1D grid 1152 (18 n x 64 m), XCD m-row chunking
  gemm_mfma<0, 128, 4><<<dim3(1152), 256, 0, stream>>>(
      xb, wqkvb, b_qkv, nullptr, Qp, Kp, Vp, BATCH * SEQ, 3 * EMBED, EMBED);

  // attn: 768 blocks (original decode), 34.8 KB LDS, 3/CU
  attn_mfma<<<dim3(BATCH * NHEAD * (SEQ / 128)), 256, 0, stream>>>(Qp, Kp, Vp, AO);

  // proj GEMM: R8-exact — 1D grid 768 (6 n x 128 m), XCD chunking, 5/CU
  gemm_mfma<1, 64, 5><<<dim3(768), 256, 0, stream>>>(
      AO, wprojb, b_proj, (float*)d_out, nullptr, nullptr, nullptr,
      BATCH * SEQ, EMBED, EMBED);
}

// Round 11
// 212.354 us; speedup vs baseline: 1.1230x; 1.0415x over previous
//
#include <hip/hip_runtime.h>
#include <hip/hip_bf16.h>
#include <math.h>

#define EMBED 768
#define NHEAD 12
#define HDIM 64
#define SEQ 2048
#define BATCH 4

typedef __hip_bfloat16 bf16;
typedef __attribute__((ext_vector_type(8))) short bf16x8;   // 8 bf16 / 4 VGPRs
typedef __attribute__((ext_vector_type(4))) short s16x4;
typedef __attribute__((ext_vector_type(4))) float f32x4;
typedef __attribute__((ext_vector_type(2))) unsigned int u32x2;

__device__ inline float b2f(bf16 v) { return __bfloat162float(v); }
__device__ inline bf16 f2b(float v) { return __float2bfloat16(v); }
__device__ inline unsigned pk2(float a, float b) {
  return (unsigned)__bfloat16_as_ushort(f2b(a)) |
         ((unsigned)__bfloat16_as_ushort(f2b(b)) << 16);
}

// async global->LDS, 16B per lane. LDS dest = wave-uniform base + lane*16.
__device__ inline void gl_lds16(const bf16* g, bf16* l) {
  __builtin_amdgcn_global_load_lds(
      (const __attribute__((address_space(1))) void*)g,
      (__attribute__((address_space(3))) void*)l, 16, 0, 0);
}

#define NX4  (BATCH * SEQ * EMBED / 4)
#define NWQ4 (3 * EMBED * EMBED / 4)
#define NWP4 (EMBED * EMBED / 4)

// ---------------------------------------------------------------------------
// One fused f32->bf16 convert for x, w_qkv, w_proj (segmented index space).
// ---------------------------------------------------------------------------
__global__ __launch_bounds__(256) void cvt_all(
    const float* __restrict__ x, const float* __restrict__ wq,
    const float* __restrict__ wp, bf16* __restrict__ xb,
    bf16* __restrict__ wqb, bf16* __restrict__ wpb) {
  int i = blockIdx.x * 256 + threadIdx.x;
  const float* src;
  bf16* dst;
  int k;
  if (i < NX4) {
    src = x; dst = xb; k = i;
  } else if (i < NX4 + NWQ4) {
    src = wq; dst = wqb; k = i - NX4;
  } else if (i < NX4 + NWQ4 + NWP4) {
    src = wp; dst = wpb; k = i - NX4 - NWQ4;
  } else {
    return;
  }
  float4 v = ((const float4*)src)[k];
  s16x4 o;
  o[0] = (short)__bfloat16_as_ushort(f2b(v.x));
  o[1] = (short)__bfloat16_as_ushort(f2b(v.y));
  o[2] = (short)__bfloat16_as_ushort(f2b(v.z));
  o[3] = (short)__bfloat16_as_ushort(f2b(v.w));
  *(s16x4*)(dst + 4 * (size_t)k) = o;
}

// ---------------------------------------------------------------------------
// MFMA GEMM — R8-exact config (the 212.2 µs best). Measured-best levers:
//   * single-buf BK=64, 2 __syncthreads/step (R2)
//   * both-sides XOR swizzle (R2)
//   * LB(256,WPB): 4-5 blocks/CU (R5)
//   * XCD m-row chunking for L2 residency (R8, FETCH-verified)
//   MODE 0 (TM=128): grid 1152; xcd=bid&7 gets m-rows [8k,8k+8) x 18 n.
//   MODE 1 (TM=64):  grid 768;  xcd=bid&7 gets m-rows [16k,16k+16) x 6 n.
// MODE 0 epilogue (verified R11/R12): Q(x 0.125*log2e)->[B,H,N,D],
// K->[B,H,N,D], V->[B,H,D,N] (bf16).  MODE 1: outF[m,o] f32 row-major.
// ---------------------------------------------------------------------------
template <int MODE, int TM, int WPB>
__global__ __launch_bounds__(256, WPB) void gemm_mfma(
    const bf16* __restrict__ A, const bf16* __restrict__ W,
    const float* __restrict__ bias, float* __restrict__ outF,
    bf16* __restrict__ outQ, bf16* __restrict__ outK, bf16* __restrict__ outV,
    int M, int N, int K) {
  __shared__ bf16 As[TM][64];
  __shared__ bf16 Bs[128][64];
  const int t = threadIdx.x;
  const int w = t >> 6;
  const int lane = t & 63;
  const int g = lane >> 4, c = lane & 15;

  // XCD locality decode (bijective)
  const int bid = blockIdx.x;
  const int xcd = bid & 7;
  const int idx = bid >> 3;
  constexpr int NT = (MODE == 0) ? 18 : 6;          // n-tiles
  constexpr int MRX = (MODE == 0) ? 8 : 16;         // m-rows per XCD
  const int mr = xcd * MRX + idx / NT;
  const int nc = idx % NT;
  const int m0 = mr * TM, n0 = nc * 128;

  constexpr int MJ = TM / 32;          // m-frags per wave: 4 (TM=128) / 2 (64)
  const int wr = (w >> 1) * (TM / 2);  // m-dim tile base (As)
  const int wc = (w & 1) * 64;         // o-dim tile base (Bs)

  // DMA mapping: 1KB per instr = 8 rows x 128B. Source chunk pre-swizzled.
  const int srow = lane >> 3;          // 0..7 row within 8-row stripe
  const int l8 = lane & 7;             // LDS 16B-slot within row
  const int sseg = (l8 ^ srow) * 8;    // swizzled global chunk (bf16 elems)

  f32x4 acc[4][MJ] = {};  // acc[i][j]: i over o-tiles (W), j over m-tiles (x)

  for (int k0 = 0; k0 < K; k0 += 64) {
#pragma unroll
    for (int i = 0; i < 4; i++) {
      int r = w * 32 + i * 8;
      gl_lds16(W + (size_t)(n0 + r + srow) * K + k0 + sseg, &Bs[r][0]);
    }
#pragma unroll
    for (int i = 0; i < TM / 32; i++) {
      int r = w * (TM / 4) + i * 8;
      gl_lds16(A + (size_t)(m0 + r + srow) * K + k0 + sseg, &As[r][0]);
    }
    __syncthreads();

#pragma unroll
    for (int h = 0; h < 2; h++) {
      bf16x8 xf[MJ], wf[4];
#pragma unroll
      for (int j = 0; j < MJ; j++)
        xf[j] = *(const bf16x8*)&As[wr + j * 16 + c][((h * 4 + g) ^ (c & 7)) * 8];
#pragma unroll
      for (int i = 0; i < 4; i++)
        wf[i] = *(const bf16x8*)&Bs[wc + i * 16 + c][((h * 4 + g) ^ (c & 7)) * 8];
#pragma unroll
      for (int i = 0; i < 4; i++)
#pragma unroll
        for (int j = 0; j < MJ; j++)
          acc[i][j] = __builtin_amdgcn_mfma_f32_16x16x32_bf16(wf[i], xf[j],
                                                              acc[i][j], 0, 0, 0);
    }
    __syncthreads();
  }

  // epilogue: D^T tile — row = o (4 consecutive per thread), col = m (lane c)
#pragma unroll
  for (int i = 0; i < 4; i++) {
    const int ob = n0 + wc + i * 16 + g * 4;     // o base, +r consecutive
    const f32x4 bv = *(const f32x4*)&bias[ob];   // 16B-aligned
    int which = 0, hh = 0, d0 = 0;
    if (MODE == 0) {
      which = ob / EMBED;
      int rem = ob - which * EMBED;
      hh = rem >> 6;
      d0 = rem & 63;
    }
#pragma unroll
    for (int j = 0; j < MJ; j++) {
      const int m = m0 + wr + j * 16 + c;
      f32x4 v = acc[i][j] + bv;
      if (MODE == 0) {
        const int bb = m >> 11, n = m & 2047;
        const size_t bh = (size_t)bb * NHEAD + hh;
        if (which == 0) {
          s16x4 q4;
#pragma unroll
          for (int r = 0; r < 4; r++)
            q4[r] = (short)__bfloat16_as_ushort(f2b(v[r] * 0.1803368801f));
          *(s16x4*)&outQ[(bh * SEQ + n) * HDIM + d0] = q4;
        } else if (which == 1) {
          s16x4 k4;
#pragma unroll
          for (int r = 0; r < 4; r++)
            k4[r] = (short)__bfloat16_as_ushort(f2b(v[r]));
          *(s16x4*)&outK[(bh * SEQ + n) * HDIM + d0] = k4;
        } else {
#pragma unroll
          for (int r = 0; r < 4; r++)
            outV[(bh * HDIM + d0 + r) * SEQ + n] = f2b(v[r]);
        }
      } else {
        *(f32x4*)&outF[(size_t)m * N + ob] = v;
      }
    }
  }
}

// ---------------------------------------------------------------------------
// Flash MFMA attention v7 + XCD swizzle — R8-exact (the 212.2 µs config).
// R10 post-mortem: the swizzle's value is NOT attn-local (dur 83.2->84.4,
// +1.2 µs) — it is the FETCH collapse 104->18.5 MB. The ~85 MB of avoided
// L2/L3 churn stops evicting the next bench-iteration's inputs (x, w_qkv,
// xb) from the 256MB L3; non-attn time was 127.8 µs (R8) vs 138.0 (R10)
// with identical gemm code. Cross-kernel L3 pollution, not drain latency.
//   Map XCD = bh&7 via bid = (bh&7) + 8*(qt + 16*(bh>>3)): per-XCD K/V set
//   = 6bh x 512KB = 3MB (L2-fits). Decode: lo=bid&7; rem=bid>>3; qt=rem&15;
//   bh=(rem>>4)*8+lo.
//   S^T = K . Q^T ; O^T = V^T . P^T  (fragment maps verified R3-R12)
// Block = 128 q-rows, 4 waves x 2 groups of 16. LDS 34.8 KB; grid 768 = 3/CU.
// Per iter: S(ks) -> B1 -> DMA K(jt+1) -> softmax/Pt/PV(vs) -> B2 -> DMA V(jt+1).
// ---------------------------------------------------------------------------
__global__ __launch_bounds__(256, 4) void attn_mfma(
    const bf16* __restrict__ Q, const bf16* __restrict__ Kk,
    const bf16* __restrict__ V, bf16* __restrict__ O) {
  __shared__ bf16 Ks[64 * 64];
  __shared__ bf16 Vts[64 * 64];
  __shared__ bf16 Pt[8][16 * 72];

  const int bid = blockIdx.x;
  const int lo = bid & 7;
  const int rem = bid >> 3;
  const int qt = rem & 15;
  const int bh = (rem >> 4) * 8 + lo;    // XCD (bid&7) <- bh&7
  const int bb = bh / NHEAD;
  const int h = bh % NHEAD;
  const int t = threadIdx.x;
  const int lane = t & 63;
  const int w = t >> 6;
  const int g = lane >> 4;
  const int c = lane & 15;
  const size_t base = (size_t)bh * SEQ * HDIM;
  const int mb0 = qt * 128 + w * 16;     // q-group 0 rows
  const int mb1 = mb0 + 64;              // q-group 1 rows

  // DMA lane mapping (XOR chunk swizzle for K/V, verified R5-R12)
  const int r8 = lane >> 3;
  const int l8 = lane & 7;
  const int gch = l8 ^ (r8 & 7);
  const int q0 = w * 2, q1 = w * 2 + 1;

  // Q fragments (B operand), one pair per q-group
  bf16x8 qa[2][2];
#pragma unroll
  for (int kh = 0; kh < 2; kh++) {
    qa[0][kh] = *(const bf16x8*)(Q + base + (size_t)(mb0 + c) * HDIM + kh * 32 + g * 8);
    qa[1][kh] = *(const bf16x8*)(Q + base + (size_t)(mb1 + c) * HDIM + kh * 32 + g * 8);
  }

  // all-ones A fragment for the l-row-sum MFMA
  bf16x8 ones;
#pragma unroll
  for (int i = 0; i < 8; i++) ones[i] = (short)0x3F80;

  f32x4 o[2][4] = {};
  f32x4 o_l[2] = {};

  // prologue: DMA tile 0 (K and V), drain before first use
  gl_lds16(Kk + base + (size_t)(q0 * 8 + r8) * HDIM + gch * 8, &Ks[q0 * 8 * 64]);
  gl_lds16(Kk + base + (size_t)(q1 * 8 + r8) * HDIM + gch * 8, &Ks[q1 * 8 * 64]);
  gl_lds16(V + base + (size_t)(q0 * 8 + r8) * SEQ + gch * 8, &Vts[q0 * 8 * 64]);
  gl_lds16(V + base + (size_t)(q1 * 8 + r8) * SEQ + gch * 8, &Vts[q1 * 8 * 64]);
  __syncthreads();

  bf16* const Pt0 = Pt[w * 2];
  bf16* const Pt1 = Pt[w * 2 + 1];

  for (int jt = 0; jt < SEQ / 64; jt++) {
    // S^T = K . Q^T — each kb read feeds both q-groups
    f32x4 s[2][4] = {};
#pragma unroll
    for (int nt = 0; nt < 4; nt++) {
#pragma unroll
      for (int kh = 0; kh < 2; kh++) {
        bf16x8 kb = *(const bf16x8*)&Ks[(nt * 16 + c) * 64 + ((kh * 4 + g) ^ (c & 7)) * 8];
        s[0][nt] = __builtin_amdgcn_mfma_f32_16x16x32_bf16(kb, qa[0][kh], s[0][nt], 0, 0, 0);
        s[1][nt] = __builtin_amdgcn_mfma_f32_16x16x32_bf16(kb, qa[1][kh], s[1][nt], 0, 0, 0);
      }
    }

    __syncthreads();  // B1: all waves done reading Ks; drains V(jt) DMA
    if (jt + 1 < SEQ / 64) {  // DMA K(jt+1); softmax+PV time to land
      const int jb = (jt + 1) * 64;
      gl_lds16(Kk + base + (size_t)(jb + q0 * 8 + r8) * HDIM + gch * 8, &Ks[q0 * 8 * 64]);
      gl_lds16(Kk + base + (size_t)(jb + q1 * 8 + r8) * HDIM + gch * 8, &Ks[q1 * 8 * 64]);
    }

    // p = exp2(s); pack 4 consecutive j; plain stride-72 Pt, per group
#pragma unroll
    for (int nt = 0; nt < 4; nt++) {
      float a0 = __builtin_amdgcn_exp2f(s[0][nt][0]);
      float a1 = __builtin_amdgcn_exp2f(s[0][nt][1]);
      float a2 = __builtin_amdgcn_exp2f(s[0][nt][2]);
      float a3 = __builtin_amdgcn_exp2f(s[0][nt][3]);
      u32x2 pw0 = {pk2(a0, a1), pk2(a2, a3)};
      *(u32x2*)&Pt0[c * 72 + nt * 16 + g * 4] = pw0;
      float b0 = __builtin_amdgcn_exp2f(s[1][nt][0]);
      float b1 = __builtin_amdgcn_exp2f(s[1][nt][1]);
      float b2 = __builtin_amdgcn_exp2f(s[1][nt][2]);
      float b3 = __builtin_amdgcn_exp2f(s[1][nt][3]);
      u32x2 pw1 = {pk2(b0, b1), pk2(b2, b3)};
      *(u32x2*)&Pt1[c * 72 + nt * 16 + g * 4] = pw1;
    }
    bf16x8 pb[2][2];
    pb[0][0] = *(const bf16x8*)&Pt0[c * 72 + g * 8];
    pb[0][1] = *(const bf16x8*)&Pt0[c * 72 + 32 + g * 8];
    pb[1][0] = *(const bf16x8*)&Pt1[c * 72 + g * 8];
    pb[1][1] = *(const bf16x8*)&Pt1[c * 72 + 32 + g * 8];

    // O^T += V^T . P^T — each vb read feeds both q-groups;
    // l += ones . P^T in the MFMA pipe
#pragma unroll
    for (int dt = 0; dt < 4; dt++) {
      bf16x8 vb0 = *(const bf16x8*)&Vts[(dt * 16 + c) * 64 + ((0 + g) ^ (c & 7)) * 8];
      bf16x8 vb1 = *(const bf16x8*)&Vts[(dt * 16 + c) * 64 + ((4 + g) ^ (c & 7)) * 8];
      o[0][dt] = __builtin_amdgcn_mfma_f32_16x16x32_bf16(vb0, pb[0][0], o[0][dt], 0, 0, 0);
      o[0][dt] = __builtin_amdgcn_mfma_f32_16x16x32_bf16(vb1, pb[0][1], o[0][dt], 0, 0, 0);
      o[1][dt] = __builtin_amdgcn_mfma_f32_16x16x32_bf16(vb0, pb[1][0], o[1][dt], 0, 0, 0);
      o[1][dt] = __builtin_amdgcn_mfma_f32_16x16x32_bf16(vb1, pb[1][1], o[1][dt], 0, 0, 0);
    }
    o_l[0] = __builtin_amdgcn_mfma_f32_16x16x32_bf16(ones, pb[0][0], o_l[0], 0, 0, 0);
    o_l[0] = __builtin_amdgcn_mfma_f32_16x16x32_bf16(ones, pb[0][1], o_l[0], 0, 0, 0);
    o_l[1] = __builtin_amdgcn_mfma_f32_16x16x32_bf16(ones, pb[1][0], o_l[1], 0, 0, 0);
    o_l[1] = __builtin_amdgcn_mfma_f32_16x16x32_bf16(ones, pb[1][1], o_l[1], 0, 0, 0);

    __syncthreads();  // B2: all waves done reading Vts; drains K(jt+1) DMA
    if (jt + 1 < SEQ / 64) {  // DMA V(jt+1); S-phase time to land
      const int jb = (jt + 1) * 64;
      gl_lds16(V + base + (size_t)(q0 * 8 + r8) * SEQ + jb + gch * 8, &Vts[q0 * 8 * 64]);
      gl_lds16(V + base + (size_t)(q1 * 8 + r8) * SEQ + jb + gch * 8, &Vts[q1 * 8 * 64]);
    }
  }

  // epilogue: l[c] replicated in every o_l reg — no shuffles; packed stores
#pragma unroll
  for (int grp = 0; grp < 2; grp++) {
    const float inv = __builtin_amdgcn_rcpf(o_l[grp][0]);
    const int mb = grp ? mb1 : mb0;
    const size_t rowoff = ((size_t)bb * SEQ + mb + c) * EMBED + h * 64 + g * 4;
#pragma unroll
    for (int dt = 0; dt < 4; dt++) {
      s16x4 ov;
#pragma unroll
      for (int r = 0; r < 4; r++)
        ov[r] = (short)__bfloat16_as_ushort(f2b(o[grp][dt][r] * inv));
      *(s16x4*)&O[rowoff + dt * 16] = ov;
    }
  }
}

// ---------------------------------------------------------------------------
extern "C" void kernel_launch(void* const* d_in, const int* in_sizes, int n_in,
                              void* d_out, int out_size, void* d_ws,
                              size_t ws_size, hipStream_t stream) {
  const float* x      = (const float*)d_in[0];
  const float* w_qkv  = (const float*)d_in[1];
  const float* b_qkv  = (const float*)d_in[2];
  const float* w_proj = (const float*)d_in[3];
  const float* b_proj = (const float*)d_in[4];

  const size_t per = (size_t)BATCH * NHEAD * SEQ * HDIM;
  bf16* Qp = (bf16*)d_ws;
  bf16* Kp = Qp + per;
  bf16* Vp = Kp + per;                 // [B,H,D,N]
  bf16* xb = Vp + per;                 // x bf16; reused as AO after QKV GEMM
  bf16* wqkvb = xb + per;
  bf16* wprojb = wqkvb + (size_t)3 * EMBED * EMBED;
  bf16* AO = xb;

  const int ncvt = NX4 + NWQ4 + NWP4;  // f32x4 groups total
  cvt_all<<<dim3((ncvt + 255) / 256), 256, 0, stream>>>(x, w_qkv, w_proj, xb,
                                                        wqkvb, wprojb);

  // QKV GEMM: 1D grid 1152 (18 n x 64 m), XCD m-row chunking
  gemm_mfma<0, 128, 4><<<dim3(1152), 256, 0, stream>>>(
      xb, wqkvb, b_qkv, nullptr, Qp, Kp, Vp, BATCH * SEQ, 3 * EMBED, EMBED);

  // attn: 768 blocks, XCD = bh&7 (K/V L2-resident per XCD; L3-churn fix)
  attn_mfma<<<dim3(BATCH * NHEAD * (SEQ / 128)), 256, 0, stream>>>(Qp, Kp, Vp, AO);

  // proj GEMM: 1D grid 768 (6 n x 128 m), XCD m-row chunking, 5 blocks/CU
  gemm_mfma<1, 64, 5><<<dim3(768), 256, 0, stream>>>(
      AO, wprojb, b_proj, (float*)d_out, nullptr, nullptr, nullptr,
      BATCH * SEQ, EMBED, EMBED);
}